// Round 6
// baseline (1996.742 us; speedup 1.0000x reference)
//
#include <hip/hip_runtime.h>
#include <math.h>
#include <stdint.h>

#define BB 1024     // batch
#define DD 512      // hidden
#define VV 10000    // vocab
#define TT 20       // steps
#define NW 50       // allowed words

// ---------------------------------------------------------------------------
// threefry2x32 block (matches jax/_src/prng.py rotation schedule exactly)
// ---------------------------------------------------------------------------
__host__ __device__ __forceinline__ void tf2x32(uint32_t k0, uint32_t k1,
                                                uint32_t x0, uint32_t x1,
                                                uint32_t& o0, uint32_t& o1) {
  uint32_t ks2 = k0 ^ k1 ^ 0x1BD11BDAu;
  x0 += k0; x1 += k1;
#define ROTL(x,r) (((x)<<(r))|((x)>>(32-(r))))
#define RND(r) { x0 += x1; x1 = ROTL(x1,(r)); x1 ^= x0; }
  RND(13) RND(15) RND(26) RND(6)   x0 += k1;  x1 += ks2 + 1u;
  RND(17) RND(29) RND(16) RND(24)  x0 += ks2; x1 += k0 + 2u;
  RND(13) RND(15) RND(26) RND(6)   x0 += k0;  x1 += k1 + 3u;
  RND(17) RND(29) RND(16) RND(24)  x0 += k1;  x1 += ks2 + 4u;
  RND(13) RND(15) RND(26) RND(6)   x0 += ks2; x1 += k0 + 5u;
#undef RND
#undef ROTL
  o0 = x0; o1 = x1;
}

__device__ __forceinline__ float wave_sum(float v) {
#pragma unroll
  for (int o = 32; o > 0; o >>= 1) v += __shfl_xor(v, o, 64);
  return v;
}
__device__ __forceinline__ float wave_max(float v) {
#pragma unroll
  for (int o = 32; o > 0; o >>= 1) v = fmaxf(v, __shfl_xor(v, o, 64));
  return v;
}

__device__ __forceinline__ float gelu_f(float x) {
  float u = x / 1.4142135623730951f;
  float e = (float)erf((double)u);      // correctly-rounded f32 erf
  return x * (e + 1.0f) * 0.5f;
}

// ---------------------------------------------------------------------------
// fp32 tiled GEMM (r3-verified, total 1563us): DOUBLE-BUFFERED LDS,
// BM=32 BN=64 BK=32, 256 threads, 2x4 micro-tile. Used for encoder + table.
// ---------------------------------------------------------------------------
template<int ACT, bool RES, bool CONCAT>
__global__ __launch_bounds__(256) void sgemm_db(
    const float* __restrict__ A, const float* __restrict__ A2, int K1,
    const float* __restrict__ W, int ldw, const float* __restrict__ bias,
    const float* __restrict__ res, float* __restrict__ C, int N, int K)
{
  __shared__ alignas(16) float As[2][32][36];   // [buf][kk][m]
  __shared__ alignas(16) float Ws[2][32][68];   // [buf][kk][n]
  const int bm = blockIdx.x * 32;
  const int bn = blockIdx.y * 64;
  const int tid = threadIdx.x;
  const int tr = (tid >> 4) << 1;   // fragment row (multiple of 2)
  const int tc = (tid & 15) << 2;   // fragment col (multiple of 4)
  // staging maps
  const int am = tid & 31;          // A row 0..31
  const int ak = (tid >> 5) << 2;   // A k-offset {0,4,...,28}
  const int wr = tid >> 3;          // W row 0..31
  const int wc = (tid & 7) << 3;    // W col {0,8,..,56}
  const int arow = bm + am;

  float4 ra, rw0, rw1;

  // ---- load tile 0 ----
  {
    int gk = ak;
    if (CONCAT) {
      ra = (gk < K1) ? *(const float4*)&A[(size_t)arow * K1 + gk]
                     : *(const float4*)&A2[(size_t)arow * (K - K1) + (gk - K1)];
    } else {
      ra = *(const float4*)&A[(size_t)arow * K + gk];
    }
    const float* wsrc = &W[(size_t)wr * ldw + bn + wc];
    rw0 = *(const float4*)(wsrc);
    rw1 = *(const float4*)(wsrc + 4);
  }
  As[0][ak + 0][am] = ra.x; As[0][ak + 1][am] = ra.y;
  As[0][ak + 2][am] = ra.z; As[0][ak + 3][am] = ra.w;
  *(float4*)&Ws[0][wr][wc]     = rw0;
  *(float4*)&Ws[0][wr][wc + 4] = rw1;
  __syncthreads();

  float acc[2][4] = {};
  int cur = 0;
  for (int k0 = 0; k0 < K; k0 += 32) {
    const bool more = (k0 + 32) < K;
    // ---- issue next tile's global loads (latency hides under compute) ----
    if (more) {
      int gk = k0 + 32 + ak;
      if (CONCAT) {
        ra = (gk < K1) ? *(const float4*)&A[(size_t)arow * K1 + gk]
                       : *(const float4*)&A2[(size_t)arow * (K - K1) + (gk - K1)];
      } else {
        ra = *(const float4*)&A[(size_t)arow * K + gk];
      }
      const float* wsrc = &W[(size_t)(k0 + 32 + wr) * ldw + bn + wc];
      rw0 = *(const float4*)(wsrc);
      rw1 = *(const float4*)(wsrc + 4);
    }
    // ---- compute on current buffer ----
    {
      const float (* __restrict__ Asc)[36] = As[cur];
      const float (* __restrict__ Wsc)[68] = Ws[cur];
#pragma unroll
      for (int kk = 0; kk < 32; kk++) {
        float a0 = Asc[kk][tr];
        float a1 = Asc[kk][tr + 1];
        float4 bv = *(const float4*)&Wsc[kk][tc];
        acc[0][0] = fmaf(a0, bv.x, acc[0][0]);
        acc[0][1] = fmaf(a0, bv.y, acc[0][1]);
        acc[0][2] = fmaf(a0, bv.z, acc[0][2]);
        acc[0][3] = fmaf(a0, bv.w, acc[0][3]);
        acc[1][0] = fmaf(a1, bv.x, acc[1][0]);
        acc[1][1] = fmaf(a1, bv.y, acc[1][1]);
        acc[1][2] = fmaf(a1, bv.z, acc[1][2]);
        acc[1][3] = fmaf(a1, bv.w, acc[1][3]);
      }
    }
    // ---- write staged regs into the other buffer, one barrier ----
    if (more) {
      int nb = cur ^ 1;
      As[nb][ak + 0][am] = ra.x; As[nb][ak + 1][am] = ra.y;
      As[nb][ak + 2][am] = ra.z; As[nb][ak + 3][am] = ra.w;
      *(float4*)&Ws[nb][wr][wc]     = rw0;
      *(float4*)&Ws[nb][wr][wc + 4] = rw1;
    }
    __syncthreads();
    cur ^= 1;
  }
  // ---- epilogue ----
#pragma unroll
  for (int i = 0; i < 2; i++) {
    int m = bm + tr + i;
#pragma unroll
    for (int j = 0; j < 4; j++) {
      int n = bn + tc + j;
      float v = acc[i][j] + bias[n];
      if (ACT == 1) v = gelu_f(v);
      if (RES) v = v + res[(size_t)m * N + n];
      C[(size_t)m * N + n] = v;
    }
  }
}

// ---------------------------------------------------------------------------
// Fused rollout step: gi-GEMM (hx @ gwi + gbi) + GRU pointwise, NO LDS.
// 256 blocks (1/CU), 256 threads. Block owns 4 rows x all 1536 cols:
//   thread col set = {tid + 256q}, q=0..5; acc[4][6].
// A (hx rows) via wave-uniform loads (scalar path); W (gwi, L2-resident)
// streamed global->regs coalesced, double-buffered in 8-kk chunks. Zero LDS
// and zero barriers in the k-loop -> escapes the LDS-pipe ~25-33% VALU cap
// measured on all LDS-fed variants (r0-r5).
// Per-output accumulation: strictly k-ascending fmaf chain, then +gbi, then
// the exact gru_pw2 formulas -> bitwise identical to the r3 pipeline.
// Gates land in-register: hidden j=tid+256*jq has r at q=jq, z at q=jq+2,
// n at q=jq+4. gi never touches memory (saves 12 MB/step of traffic).
// In-place hx update is safe: block reads only its own 4 rows (all reads
// precede the epilogue writes).
// ---------------------------------------------------------------------------
__device__ __forceinline__ void load_w6x8(float w[6][8],
                                          const float* __restrict__ Wt, int kb) {
#pragma unroll
  for (int q = 0; q < 6; q++)
#pragma unroll
    for (int kk = 0; kk < 8; kk++)
      w[q][kk] = Wt[(size_t)(kb + kk) * 1536 + (q << 8)];
}

__device__ __forceinline__ void load_a4x8(float a[4][8],
                                          const float* __restrict__ hxr, int kb) {
#pragma unroll
  for (int r = 0; r < 4; r++) {
    float4 x = *(const float4*)(hxr + (size_t)r * DD + kb);
    float4 y = *(const float4*)(hxr + (size_t)r * DD + kb + 4);
    a[r][0] = x.x; a[r][1] = x.y; a[r][2] = x.z; a[r][3] = x.w;
    a[r][4] = y.x; a[r][5] = y.y; a[r][6] = y.z; a[r][7] = y.w;
  }
}

__device__ __forceinline__ void fma4x6x8(float acc[4][6],
                                         const float a[4][8], const float w[6][8]) {
#pragma unroll
  for (int kk = 0; kk < 8; kk++)      // kk outer: k-ascending per output
#pragma unroll
    for (int r = 0; r < 4; r++)
#pragma unroll
      for (int q = 0; q < 6; q++)
        acc[r][q] = fmaf(a[r][kk], w[q][kk], acc[r][q]);
}

__global__ __launch_bounds__(256, 1) void step_fused(
    const float* __restrict__ gwi, const float* __restrict__ gbi,
    const float* __restrict__ table, const float* __restrict__ gbh,
    const float* __restrict__ emb, const float* __restrict__ out,
    int t, float* __restrict__ hx)
{
  const int r0 = blockIdx.x * 4;
  const int tid = threadIdx.x;
  const float* __restrict__ Wt = gwi + tid;                 // per-lane col base
  const float* __restrict__ hxr = hx + (size_t)r0 * DD;     // wave-uniform

  float acc[4][6] = {};
  float wA[6][8], wB[6][8], aA[4][8], aB[4][8];

  load_w6x8(wA, Wt, 0);
  load_a4x8(aA, hxr, 0);
  for (int kb = 0; kb < DD; kb += 16) {
    load_w6x8(wB, Wt, kb + 8);
    load_a4x8(aB, hxr, kb + 8);
    fma4x6x8(acc, aA, wA);
    if (kb + 16 < DD) {
      load_w6x8(wA, Wt, kb + 16);
      load_a4x8(aA, hxr, kb + 16);
    }
    fma4x6x8(acc, aB, wB);
  }

  // + gbi (matches sgemm epilogue: v = acc + bias)
#pragma unroll
  for (int r = 0; r < 4; r++)
#pragma unroll
    for (int q = 0; q < 6; q++)
      acc[r][q] += gbi[tid + (q << 8)];

  // GRU pointwise (exact gru_pw2 formulas)
#pragma unroll
  for (int r = 0; r < 4; r++) {
    const float* ghb;
    const float* er = nullptr;
    if (t == 0) {
      ghb = gbh;
    } else {
      int a = (int)out[(size_t)(r0 + r) * TT + (t - 1)];
      ghb = table + (size_t)a * 1536;
      er = emb + (size_t)a * DD;
    }
#pragma unroll
    for (int jq = 0; jq < 2; jq++) {
      int j = tid + (jq << 8);
      float ixv = (t == 0) ? 0.f : er[j];
      float rr = (float)(1.0 / (1.0 + exp(-(double)(acc[r][jq] + ghb[j]))));
      float zz = (float)(1.0 / (1.0 + exp(-(double)(acc[r][jq + 2] + ghb[DD + j]))));
      float narg = acc[r][jq + 4] + rr * ghb[2 * DD + j];
      float nn = (float)tanh((double)narg);
      hx[(size_t)(r0 + r) * DD + j] = (1.0f - zz) * nn + zz * ixv;
    }
  }
}

// ---------------------------------------------------------------------------
// LayerNorm over D=512
// ---------------------------------------------------------------------------
template<bool AFFINE, bool ADD>
__global__ __launch_bounds__(256) void lnorm_k(
    const float* __restrict__ X, const float* __restrict__ X2,
    const float* __restrict__ g, const float* __restrict__ bt,
    float* __restrict__ Y)
{
  __shared__ float red[8];
  int row = blockIdx.x, tid = threadIdx.x;
  const float* x = X + (size_t)row * DD;
  float v0 = x[tid], v1 = x[tid + 256];
  if (ADD) {
    const float* x2 = X2 + (size_t)row * DD;
    v0 += x2[tid]; v1 += x2[tid + 256];
  }
  float s = wave_sum(v0 + v1);
  if ((tid & 63) == 0) red[tid >> 6] = s;
  __syncthreads();
  float mean = (red[0] + red[1] + red[2] + red[3]) * (1.0f / 512.0f);
  float d0 = v0 - mean, d1 = v1 - mean;
  float s2 = wave_sum(d0 * d0 + d1 * d1);
  if ((tid & 63) == 0) red[4 + (tid >> 6)] = s2;
  __syncthreads();
  float var = (red[4] + red[5] + red[6] + red[7]) * (1.0f / 512.0f);
  float rs = (float)(1.0 / sqrt((double)(var + 1e-5f)));
  float y0 = d0 * rs, y1 = d1 * rs;
  if (AFFINE) {
    y0 = y0 * g[tid] + bt[tid];
    y1 = y1 * g[tid + 256] + bt[tid + 256];
  }
  Y[(size_t)row * DD + tid] = y0;
  Y[(size_t)row * DD + tid + 256] = y1;
}

// ---------------------------------------------------------------------------
// Fused actor/critic heads + sampling (r3-proven, absmax 5.96e-08).
// 128 threads per row: wave0 = actor chain + sampling, wave1 = critic chain.
// ---------------------------------------------------------------------------
__global__ __launch_bounds__(128) void head_sample2(
    const float* __restrict__ hx,
    const float* __restrict__ a1w, const float* __restrict__ a1b,
    const float* __restrict__ a2w, const float* __restrict__ a2b,
    const float* __restrict__ a3w, const float* __restrict__ a3b,
    const float* __restrict__ c1w, const float* __restrict__ c1b,
    const float* __restrict__ c2w, const float* __restrict__ c2b,
    const float* __restrict__ c3w, const float* __restrict__ c3b,
    const float* __restrict__ wmask,
    float* __restrict__ out,
    int t, uint32_t fk0, uint32_t fk1)
{
  int b = blockIdx.x;
  int tid = threadIdx.x;
  int lane = tid & 63;
  __shared__ float sh[DD];
  __shared__ float st1[64], st2[64], sc1[64];
  const float* hr = hx + (size_t)b * DD;
  for (int i = tid; i < DD; i += 128) sh[i] = hr[i];
  __syncthreads();

  if (tid < 64) {
    // ------------------- actor wave -------------------
    float aa0 = 0, aa1 = 0, aa2 = 0, aa3 = 0;
    for (int k = 0; k < DD; k += 4) {
      float h0 = sh[k], h1 = sh[k + 1], h2 = sh[k + 2], h3 = sh[k + 3];
      aa0 = fmaf(h0, a1w[(k + 0) * 64 + lane], aa0);
      aa1 = fmaf(h1, a1w[(k + 1) * 64 + lane], aa1);
      aa2 = fmaf(h2, a1w[(k + 2) * 64 + lane], aa2);
      aa3 = fmaf(h3, a1w[(k + 3) * 64 + lane], aa3);
    }
    st1[lane] = (float)tanh((double)(((aa0 + aa1) + (aa2 + aa3)) + a1b[lane]));

    float a2acc = 0;
    for (int k = 0; k < 64; k++)
      a2acc = fmaf(st1[k], a2w[k * 64 + lane], a2acc);
    st2[lane] = (float)tanh((double)(a2acc + a2b[lane]));

    float lg = -INFINITY;
    if (lane < NW) {
      float s = 0;
      for (int k = 0; k < 64; k++) s = fmaf(st2[k], a3w[k * VV + lane], s);
      lg = (s + a3b[lane]) + wmask[lane];
    }

    float m = wave_max(lg);
    float shf = 0.f, e = 0.f;
    if (lane < NW) { shf = lg - m; e = (float)exp((double)shf); }
    float se = wave_sum(e);
    float lse = (float)log((double)se);
    float logp = shf - lse;
    float term = 0.f;
    if (lane < NW) { float p = (float)exp((double)logp); term = p * logp; }
    float ent = -wave_sum(term);

    // gumbel: partitionable threefry, XOR fold
    float score = -INFINITY;
    if (lane < NW) {
      uint32_t i = (uint32_t)b * (uint32_t)VV + (uint32_t)lane;
      uint32_t o0, o1;
      tf2x32(fk0, fk1, 0u, i, o0, o1);
      uint32_t bits = o0 ^ o1;
      uint32_t mant = bits >> 9;
      float u = (mant == 0u) ? 1.17549435e-38f
                             : (float)mant * 1.1920928955078125e-7f;
      float l1 = (float)log((double)u);
      float l2 = (float)log((double)(-l1));
      score = -l2 + logp;
    }

    float best = score; int bi = lane;
#pragma unroll
    for (int off = 32; off > 0; off >>= 1) {
      float ob = __shfl_xor(best, off, 64);
      int oi = __shfl_xor(bi, off, 64);
      if (ob > best || (ob == best && oi < bi)) { best = ob; bi = oi; }
    }
    float lp = __shfl(logp, bi, 64);

    if (lane == 0) {
      out[(size_t)b * TT + t] = (float)bi;
      out[(size_t)BB * TT + (size_t)b * TT + t] = lp;
      out[2 * (size_t)BB * TT + (size_t)b * TT + t] = ent;
    }
  } else {
    // ------------------- critic wave -------------------
    float ca0 = 0, ca1 = 0, ca2 = 0, ca3 = 0;
    for (int k = 0; k < DD; k += 4) {
      float h0 = sh[k], h1 = sh[k + 1], h2 = sh[k + 2], h3 = sh[k + 3];
      ca0 = fmaf(h0, c1w[(k + 0) * 64 + lane], ca0);
      ca1 = fmaf(h1, c1w[(k + 1) * 64 + lane], ca1);
      ca2 = fmaf(h2, c1w[(k + 2) * 64 + lane], ca2);
      ca3 = fmaf(h3, c1w[(k + 3) * 64 + lane], ca3);
    }
    sc1[lane] = (float)tanh((double)(((ca0 + ca1) + (ca2 + ca3)) + c1b[lane]));

    float c2acc = 0;
    for (int k = 0; k < 64; k++)
      c2acc = fmaf(sc1[k], c2w[k * 64 + lane], c2acc);
    float t2c = (float)tanh((double)(c2acc + c2b[lane]));

    float val = wave_sum(t2c * c3w[lane]) + c3b[0];
    if (lane == 0)
      out[3 * (size_t)BB * TT + (size_t)b * TT + t] = val;
  }
}

// ---------------------------------------------------------------------------
// Diagnostic channel
// ---------------------------------------------------------------------------
__global__ __launch_bounds__(256) void diag_k(float* out, float code, int n) {
  int i = blockIdx.x * 256 + threadIdx.x;
  if (i < n) out[i] = code;
}

// ---------------------------------------------------------------------------
extern "C" void kernel_launch(void* const* d_in, const int* in_sizes, int n_in,
                              void* d_out, int out_size, void* d_ws, size_t ws_size,
                              hipStream_t stream) {
  static const int EXP_SIZES[34] = {
    2097152, 262144, 1179648, 512, 262144, 512, 262144, 512, 262144, 512,
    262144, 512, 512, 512, 262144, 512, 5120000, 786432, 786432, 1536,
    1536, 32768, 64, 4096, 64, 640000, 10000, 32768, 64, 4096,
    64, 64, 1, 10000 };
  double code = 0.0;
  if (n_in != 34) code = 1e6 + (double)n_in;
  else {
    for (int i = 0; i < 34; i++)
      if (in_sizes[i] != EXP_SIZES[i]) { code = 2e6 + i * 1e4 + (in_sizes[i] % 10000); break; }
  }
  if (code == 0.0 && out_size != 4 * BB * TT) code = 3e6 + (double)(out_size % 1000000);
  if (code == 0.0 && ws_size < (size_t)24 * 1024 * 1024) {
    size_t kb = ws_size / 1024; if (kb > 999999) kb = 999999;
    code = 4e6 + (double)kb;
  }
  if (code != 0.0) {
    diag_k<<<(out_size + 255) / 256, 256, 0, stream>>>((float*)d_out, (float)code, out_size);
    return;
  }

  const float* image = (const float*)d_in[0];
  const float* boxf  = (const float*)d_in[1];
  const float* fr_w  = (const float*)d_in[2];
  const float* fr_b  = (const float*)d_in[3];
  const float* d1a_w = (const float*)d_in[4];
  const float* d1a_b = (const float*)d_in[5];
  const float* d1b_w = (const float*)d_in[6];
  const float* d1b_b = (const float*)d_in[7];
  const float* d2a_w = (const float*)d_in[8];
  const float* d2a_b = (const float*)d_in[9];
  const float* d2b_w = (const float*)d_in[10];
  const float* d2b_b = (const float*)d_in[11];
  const float* ln_g  = (const float*)d_in[12];
  const float* ln_b  = (const float*)d_in[13];
  const float* eo_w  = (const float*)d_in[14];
  const float* eo_b  = (const float*)d_in[15];
  const float* emb   = (const float*)d_in[16];
  const float* gwi   = (const float*)d_in[17];
  const float* gwh   = (const float*)d_in[18];
  const float* gbi   = (const float*)d_in[19];
  const float* gbh   = (const float*)d_in[20];
  const float* a1w   = (const float*)d_in[21];
  const float* a1b   = (const float*)d_in[22];
  const float* a2w   = (const float*)d_in[23];
  const float* a2b   = (const float*)d_in[24];
  const float* a3w   = (const float*)d_in[25];
  const float* a3b   = (const float*)d_in[26];
  const float* c1w   = (const float*)d_in[27];
  const float* c1b   = (const float*)d_in[28];
  const float* c2w   = (const float*)d_in[29];
  const float* c2b   = (const float*)d_in[30];
  const float* c3w   = (const float*)d_in[31];
  const float* c3b   = (const float*)d_in[32];
  const float* wmask = (const float*)d_in[33];

  float* ws = (float*)d_ws;
  const size_t R = (size_t)BB * DD;          // 524288 floats
  float* hx    = ws;                          // [B,512]
  float* gi    = ws + R;                      // encoder scratch region
  float* table = ws + 4 * R;                  // [64,1536] (rows 0..49 used + junk)
  // encoder scratch aliases gi region (dead before rollout starts):
  float* P = gi;              // x0
  float* Q = gi + R;          // tA
  float* S = gi + 2 * R;      // tB
  float* U = ws + 4 * R + 2 * R;  // y/x scratch (beyond table, < 24 MiB total)
  float* out = (float*)d_out;

  dim3 blk(256);
  // gh table: rows v<64 of emb @ gwh + gbh (only v<50 ever gathered)
  sgemm_db<0, false, false><<<dim3(2, 24), blk, 0, stream>>>(emb, nullptr, 0, gwh, 1536, gbh, nullptr, table, 1536, 512);
  // encoder
  sgemm_db<0, false, true><<<dim3(32, 8), blk, 0, stream>>>(image, boxf, 2048, fr_w, 512, fr_b, nullptr, P, 512, 2304);
  lnorm_k<false, false><<<BB, blk, 0, stream>>>(P, nullptr, nullptr, nullptr, Q);
  sgemm_db<1, false, false><<<dim3(32, 8), blk, 0, stream>>>(Q, nullptr, 0, d1a_w, 512, d1a_b, nullptr, S, 512, 512);
  sgemm_db<0, false, false><<<dim3(32, 8), blk, 0, stream>>>(S, nullptr, 0, d1b_w, 512, d1b_b, nullptr, U, 512, 512);
  lnorm_k<false, true><<<BB, blk, 0, stream>>>(U, P, nullptr, nullptr, Q);
  sgemm_db<1, false, false><<<dim3(32, 8), blk, 0, stream>>>(Q, nullptr, 0, d2a_w, 512, d2a_b, nullptr, S, 512, 512);
  sgemm_db<0, true, false><<<dim3(32, 8), blk, 0, stream>>>(S, nullptr, 0, d2b_w, 512, d2b_b, P, U, 512, 512);
  lnorm_k<true, false><<<BB, blk, 0, stream>>>(U, nullptr, ln_g, ln_b, Q);
  sgemm_db<0, false, false><<<dim3(32, 8), blk, 0, stream>>>(Q, nullptr, 0, eo_w, 512, eo_b, nullptr, hx, 512, 512);

  // rollout: fused GEMM+GRU (no LDS, L2-streamed W) then heads+sampling
  for (int t = 0; t < TT; t++) {
    uint32_t fk0, fk1;
    tf2x32(0u, 1u, 0u, (uint32_t)t, fk0, fk1);   // fold_in(key(1), t)
    step_fused<<<256, blk, 0, stream>>>(gwi, gbi, table, gbh, emb, out, t, hx);
    head_sample2<<<BB, dim3(128), 0, stream>>>(hx, a1w, a1b, a2w, a2b, a3w, a3b,
                                               c1w, c1b, c2w, c2b, c3w, c3b,
                                               wmask, out, t, fk0, fk1);
  }
}

// Round 7
// 1519.127 us; speedup vs baseline: 1.3144x; 1.3144x over previous
//
#include <hip/hip_runtime.h>
#include <math.h>
#include <stdint.h>

#define BB 1024     // batch
#define DD 512      // hidden
#define VV 10000    // vocab
#define TT 20       // steps
#define NW 50       // allowed words

// ---------------------------------------------------------------------------
// threefry2x32 block (matches jax/_src/prng.py rotation schedule exactly)
// ---------------------------------------------------------------------------
__host__ __device__ __forceinline__ void tf2x32(uint32_t k0, uint32_t k1,
                                                uint32_t x0, uint32_t x1,
                                                uint32_t& o0, uint32_t& o1) {
  uint32_t ks2 = k0 ^ k1 ^ 0x1BD11BDAu;
  x0 += k0; x1 += k1;
#define ROTL(x,r) (((x)<<(r))|((x)>>(32-(r))))
#define RND(r) { x0 += x1; x1 = ROTL(x1,(r)); x1 ^= x0; }
  RND(13) RND(15) RND(26) RND(6)   x0 += k1;  x1 += ks2 + 1u;
  RND(17) RND(29) RND(16) RND(24)  x0 += ks2; x1 += k0 + 2u;
  RND(13) RND(15) RND(26) RND(6)   x0 += k0;  x1 += k1 + 3u;
  RND(17) RND(29) RND(16) RND(24)  x0 += k1;  x1 += ks2 + 4u;
  RND(13) RND(15) RND(26) RND(6)   x0 += ks2; x1 += k0 + 5u;
#undef RND
#undef ROTL
  o0 = x0; o1 = x1;
}

__device__ __forceinline__ float wave_sum(float v) {
#pragma unroll
  for (int o = 32; o > 0; o >>= 1) v += __shfl_xor(v, o, 64);
  return v;
}
__device__ __forceinline__ float wave_max(float v) {
#pragma unroll
  for (int o = 32; o > 0; o >>= 1) v = fmaxf(v, __shfl_xor(v, o, 64));
  return v;
}

__device__ __forceinline__ float gelu_f(float x) {
  float u = x / 1.4142135623730951f;
  float e = (float)erf((double)u);      // correctly-rounded f32 erf
  return x * (e + 1.0f) * 0.5f;
}

// ---------------------------------------------------------------------------
// fp32 tiled GEMM (r3-verified best, total 1563us): DOUBLE-BUFFERED LDS,
// BM=32 BN=64 BK=32, 256 threads, 2x4 micro-tile. UNCHANGED from r3.
// ---------------------------------------------------------------------------
template<int ACT, bool RES, bool CONCAT>
__global__ __launch_bounds__(256) void sgemm_db(
    const float* __restrict__ A, const float* __restrict__ A2, int K1,
    const float* __restrict__ W, int ldw, const float* __restrict__ bias,
    const float* __restrict__ res, float* __restrict__ C, int N, int K)
{
  __shared__ alignas(16) float As[2][32][36];   // [buf][kk][m]
  __shared__ alignas(16) float Ws[2][32][68];   // [buf][kk][n]
  const int bm = blockIdx.x * 32;
  const int bn = blockIdx.y * 64;
  const int tid = threadIdx.x;
  const int tr = (tid >> 4) << 1;   // fragment row (multiple of 2)
  const int tc = (tid & 15) << 2;   // fragment col (multiple of 4)
  // staging maps
  const int am = tid & 31;          // A row 0..31
  const int ak = (tid >> 5) << 2;   // A k-offset {0,4,...,28}
  const int wr = tid >> 3;          // W row 0..31
  const int wc = (tid & 7) << 3;    // W col {0,8,..,56}
  const int arow = bm + am;

  float4 ra, rw0, rw1;

  // ---- load tile 0 ----
  {
    int gk = ak;
    if (CONCAT) {
      ra = (gk < K1) ? *(const float4*)&A[(size_t)arow * K1 + gk]
                     : *(const float4*)&A2[(size_t)arow * (K - K1) + (gk - K1)];
    } else {
      ra = *(const float4*)&A[(size_t)arow * K + gk];
    }
    const float* wsrc = &W[(size_t)wr * ldw + bn + wc];
    rw0 = *(const float4*)(wsrc);
    rw1 = *(const float4*)(wsrc + 4);
  }
  As[0][ak + 0][am] = ra.x; As[0][ak + 1][am] = ra.y;
  As[0][ak + 2][am] = ra.z; As[0][ak + 3][am] = ra.w;
  *(float4*)&Ws[0][wr][wc]     = rw0;
  *(float4*)&Ws[0][wr][wc + 4] = rw1;
  __syncthreads();

  float acc[2][4] = {};
  int cur = 0;
  for (int k0 = 0; k0 < K; k0 += 32) {
    const bool more = (k0 + 32) < K;
    // ---- issue next tile's global loads (latency hides under compute) ----
    if (more) {
      int gk = k0 + 32 + ak;
      if (CONCAT) {
        ra = (gk < K1) ? *(const float4*)&A[(size_t)arow * K1 + gk]
                       : *(const float4*)&A2[(size_t)arow * (K - K1) + (gk - K1)];
      } else {
        ra = *(const float4*)&A[(size_t)arow * K + gk];
      }
      const float* wsrc = &W[(size_t)(k0 + 32 + wr) * ldw + bn + wc];
      rw0 = *(const float4*)(wsrc);
      rw1 = *(const float4*)(wsrc + 4);
    }
    // ---- compute on current buffer ----
    {
      const float (* __restrict__ Asc)[36] = As[cur];
      const float (* __restrict__ Wsc)[68] = Ws[cur];
#pragma unroll
      for (int kk = 0; kk < 32; kk++) {
        float a0 = Asc[kk][tr];
        float a1 = Asc[kk][tr + 1];
        float4 bv = *(const float4*)&Wsc[kk][tc];
        acc[0][0] = fmaf(a0, bv.x, acc[0][0]);
        acc[0][1] = fmaf(a0, bv.y, acc[0][1]);
        acc[0][2] = fmaf(a0, bv.z, acc[0][2]);
        acc[0][3] = fmaf(a0, bv.w, acc[0][3]);
        acc[1][0] = fmaf(a1, bv.x, acc[1][0]);
        acc[1][1] = fmaf(a1, bv.y, acc[1][1]);
        acc[1][2] = fmaf(a1, bv.z, acc[1][2]);
        acc[1][3] = fmaf(a1, bv.w, acc[1][3]);
      }
    }
    // ---- write staged regs into the other buffer, one barrier ----
    if (more) {
      int nb = cur ^ 1;
      As[nb][ak + 0][am] = ra.x; As[nb][ak + 1][am] = ra.y;
      As[nb][ak + 2][am] = ra.z; As[nb][ak + 3][am] = ra.w;
      *(float4*)&Ws[nb][wr][wc]     = rw0;
      *(float4*)&Ws[nb][wr][wc + 4] = rw1;
    }
    __syncthreads();
    cur ^= 1;
  }
  // ---- epilogue ----
#pragma unroll
  for (int i = 0; i < 2; i++) {
    int m = bm + tr + i;
#pragma unroll
    for (int j = 0; j < 4; j++) {
      int n = bn + tc + j;
      float v = acc[i][j] + bias[n];
      if (ACT == 1) v = gelu_f(v);
      if (RES) v = v + res[(size_t)m * N + n];
      C[(size_t)m * N + n] = v;
    }
  }
}

// ---------------------------------------------------------------------------
// LayerNorm over D=512
// ---------------------------------------------------------------------------
template<bool AFFINE, bool ADD>
__global__ __launch_bounds__(256) void lnorm_k(
    const float* __restrict__ X, const float* __restrict__ X2,
    const float* __restrict__ g, const float* __restrict__ bt,
    float* __restrict__ Y)
{
  __shared__ float red[8];
  int row = blockIdx.x, tid = threadIdx.x;
  const float* x = X + (size_t)row * DD;
  float v0 = x[tid], v1 = x[tid + 256];
  if (ADD) {
    const float* x2 = X2 + (size_t)row * DD;
    v0 += x2[tid]; v1 += x2[tid + 256];
  }
  float s = wave_sum(v0 + v1);
  if ((tid & 63) == 0) red[tid >> 6] = s;
  __syncthreads();
  float mean = (red[0] + red[1] + red[2] + red[3]) * (1.0f / 512.0f);
  float d0 = v0 - mean, d1 = v1 - mean;
  float s2 = wave_sum(d0 * d0 + d1 * d1);
  if ((tid & 63) == 0) red[4 + (tid >> 6)] = s2;
  __syncthreads();
  float var = (red[4] + red[5] + red[6] + red[7]) * (1.0f / 512.0f);
  float rs = (float)(1.0 / sqrt((double)(var + 1e-5f)));
  float y0 = d0 * rs, y1 = d1 * rs;
  if (AFFINE) {
    y0 = y0 * g[tid] + bt[tid];
    y1 = y1 * g[tid + 256] + bt[tid + 256];
  }
  Y[(size_t)row * DD + tid] = y0;
  Y[(size_t)row * DD + tid + 256] = y1;
}

// ---------------------------------------------------------------------------
// Fused GRU pointwise + actor/critic heads + sampling (formulas verified
// passing in r2/r4/r5). One 128-thread block per batch row. Phase 1: GRU
// pointwise (4 elems/thread, exact gru_pw2 formulas), writing hx to global
// AND LDS. Phase 2: wave0 = actor chain + sampling, wave1 = critic chain.
// Saves 20 launches + one hx global read pass per step vs the r3 structure.
// ---------------------------------------------------------------------------
__global__ __launch_bounds__(128) void gru_head(
    const float* __restrict__ gi, const float* __restrict__ table,
    const float* __restrict__ gbh, const float* __restrict__ emb,
    float* __restrict__ hx,
    const float* __restrict__ a1w, const float* __restrict__ a1b,
    const float* __restrict__ a2w, const float* __restrict__ a2b,
    const float* __restrict__ a3w, const float* __restrict__ a3b,
    const float* __restrict__ c1w, const float* __restrict__ c1b,
    const float* __restrict__ c2w, const float* __restrict__ c2b,
    const float* __restrict__ c3w, const float* __restrict__ c3b,
    const float* __restrict__ wmask,
    float* __restrict__ out,
    int t, uint32_t fk0, uint32_t fk1)
{
  int b = blockIdx.x;
  int tid = threadIdx.x;
  int lane = tid & 63;
  __shared__ float sh[DD];
  __shared__ float st1[64], st2[64], sc1[64];

  // ---- phase 1: GRU pointwise for this row ----
  {
    const float* ghb;
    const float* er = nullptr;
    if (t == 0) {
      ghb = gbh;
    } else {
      int a = (int)out[(size_t)b * TT + (t - 1)];
      ghb = table + (size_t)a * 1536;
      er = emb + (size_t)a * DD;
    }
    const float* gib = gi + (size_t)b * 1536;
#pragma unroll
    for (int q = 0; q < 4; q++) {
      int j = tid + 128 * q;
      float ixv = (t == 0) ? 0.f : er[j];
      float r = (float)(1.0 / (1.0 + exp(-(double)(gib[j] + ghb[j]))));
      float z = (float)(1.0 / (1.0 + exp(-(double)(gib[DD + j] + ghb[DD + j]))));
      float narg = gib[2 * DD + j] + r * ghb[2 * DD + j];
      float n = (float)tanh((double)narg);
      float h = (1.0f - z) * n + z * ixv;
      hx[(size_t)b * DD + j] = h;
      sh[j] = h;
    }
  }
  __syncthreads();

  // ---- phase 2: heads ----
  if (tid < 64) {
    // ------------------- actor wave -------------------
    float aa0 = 0, aa1 = 0, aa2 = 0, aa3 = 0;
    for (int k = 0; k < DD; k += 4) {
      float h0 = sh[k], h1 = sh[k + 1], h2 = sh[k + 2], h3 = sh[k + 3];
      aa0 = fmaf(h0, a1w[(k + 0) * 64 + lane], aa0);
      aa1 = fmaf(h1, a1w[(k + 1) * 64 + lane], aa1);
      aa2 = fmaf(h2, a1w[(k + 2) * 64 + lane], aa2);
      aa3 = fmaf(h3, a1w[(k + 3) * 64 + lane], aa3);
    }
    st1[lane] = (float)tanh((double)(((aa0 + aa1) + (aa2 + aa3)) + a1b[lane]));

    float a2acc = 0;
    for (int k = 0; k < 64; k++)
      a2acc = fmaf(st1[k], a2w[k * 64 + lane], a2acc);
    st2[lane] = (float)tanh((double)(a2acc + a2b[lane]));

    float lg = -INFINITY;
    if (lane < NW) {
      float s = 0;
      for (int k = 0; k < 64; k++) s = fmaf(st2[k], a3w[k * VV + lane], s);
      lg = (s + a3b[lane]) + wmask[lane];
    }

    float m = wave_max(lg);
    float shf = 0.f, e = 0.f;
    if (lane < NW) { shf = lg - m; e = (float)exp((double)shf); }
    float se = wave_sum(e);
    float lse = (float)log((double)se);
    float logp = shf - lse;
    float term = 0.f;
    if (lane < NW) { float p = (float)exp((double)logp); term = p * logp; }
    float ent = -wave_sum(term);

    // gumbel: partitionable threefry, XOR fold
    float score = -INFINITY;
    if (lane < NW) {
      uint32_t i = (uint32_t)b * (uint32_t)VV + (uint32_t)lane;
      uint32_t o0, o1;
      tf2x32(fk0, fk1, 0u, i, o0, o1);
      uint32_t bits = o0 ^ o1;
      uint32_t mant = bits >> 9;
      float u = (mant == 0u) ? 1.17549435e-38f
                             : (float)mant * 1.1920928955078125e-7f;
      float l1 = (float)log((double)u);
      float l2 = (float)log((double)(-l1));
      score = -l2 + logp;
    }

    float best = score; int bi = lane;
#pragma unroll
    for (int off = 32; off > 0; off >>= 1) {
      float ob = __shfl_xor(best, off, 64);
      int oi = __shfl_xor(bi, off, 64);
      if (ob > best || (ob == best && oi < bi)) { best = ob; bi = oi; }
    }
    float lp = __shfl(logp, bi, 64);

    if (lane == 0) {
      out[(size_t)b * TT + t] = (float)bi;
      out[(size_t)BB * TT + (size_t)b * TT + t] = lp;
      out[2 * (size_t)BB * TT + (size_t)b * TT + t] = ent;
    }
  } else {
    // ------------------- critic wave -------------------
    float ca0 = 0, ca1 = 0, ca2 = 0, ca3 = 0;
    for (int k = 0; k < DD; k += 4) {
      float h0 = sh[k], h1 = sh[k + 1], h2 = sh[k + 2], h3 = sh[k + 3];
      ca0 = fmaf(h0, c1w[(k + 0) * 64 + lane], ca0);
      ca1 = fmaf(h1, c1w[(k + 1) * 64 + lane], ca1);
      ca2 = fmaf(h2, c1w[(k + 2) * 64 + lane], ca2);
      ca3 = fmaf(h3, c1w[(k + 3) * 64 + lane], ca3);
    }
    sc1[lane] = (float)tanh((double)(((ca0 + ca1) + (ca2 + ca3)) + c1b[lane]));

    float c2acc = 0;
    for (int k = 0; k < 64; k++)
      c2acc = fmaf(sc1[k], c2w[k * 64 + lane], c2acc);
    float t2c = (float)tanh((double)(c2acc + c2b[lane]));

    float val = wave_sum(t2c * c3w[lane]) + c3b[0];
    if (lane == 0)
      out[3 * (size_t)BB * TT + (size_t)b * TT + t] = val;
  }
}

// ---------------------------------------------------------------------------
// Diagnostic channel
// ---------------------------------------------------------------------------
__global__ __launch_bounds__(256) void diag_k(float* out, float code, int n) {
  int i = blockIdx.x * 256 + threadIdx.x;
  if (i < n) out[i] = code;
}

// ---------------------------------------------------------------------------
extern "C" void kernel_launch(void* const* d_in, const int* in_sizes, int n_in,
                              void* d_out, int out_size, void* d_ws, size_t ws_size,
                              hipStream_t stream) {
  static const int EXP_SIZES[34] = {
    2097152, 262144, 1179648, 512, 262144, 512, 262144, 512, 262144, 512,
    262144, 512, 512, 512, 262144, 512, 5120000, 786432, 786432, 1536,
    1536, 32768, 64, 4096, 64, 640000, 10000, 32768, 64, 4096,
    64, 64, 1, 10000 };
  double code = 0.0;
  if (n_in != 34) code = 1e6 + (double)n_in;
  else {
    for (int i = 0; i < 34; i++)
      if (in_sizes[i] != EXP_SIZES[i]) { code = 2e6 + i * 1e4 + (in_sizes[i] % 10000); break; }
  }
  if (code == 0.0 && out_size != 4 * BB * TT) code = 3e6 + (double)(out_size % 1000000);
  if (code == 0.0 && ws_size < (size_t)24 * 1024 * 1024) {
    size_t kb = ws_size / 1024; if (kb > 999999) kb = 999999;
    code = 4e6 + (double)kb;
  }
  if (code != 0.0) {
    diag_k<<<(out_size + 255) / 256, 256, 0, stream>>>((float*)d_out, (float)code, out_size);
    return;
  }

  const float* image = (const float*)d_in[0];
  const float* boxf  = (const float*)d_in[1];
  const float* fr_w  = (const float*)d_in[2];
  const float* fr_b  = (const float*)d_in[3];
  const float* d1a_w = (const float*)d_in[4];
  const float* d1a_b = (const float*)d_in[5];
  const float* d1b_w = (const float*)d_in[6];
  const float* d1b_b = (const float*)d_in[7];
  const float* d2a_w = (const float*)d_in[8];
  const float* d2a_b = (const float*)d_in[9];
  const float* d2b_w = (const float*)d_in[10];
  const float* d2b_b = (const float*)d_in[11];
  const float* ln_g  = (const float*)d_in[12];
  const float* ln_b  = (const float*)d_in[13];
  const float* eo_w  = (const float*)d_in[14];
  const float* eo_b  = (const float*)d_in[15];
  const float* emb   = (const float*)d_in[16];
  const float* gwi   = (const float*)d_in[17];
  const float* gwh   = (const float*)d_in[18];
  const float* gbi   = (const float*)d_in[19];
  const float* gbh   = (const float*)d_in[20];
  const float* a1w   = (const float*)d_in[21];
  const float* a1b   = (const float*)d_in[22];
  const float* a2w   = (const float*)d_in[23];
  const float* a2b   = (const float*)d_in[24];
  const float* a3w   = (const float*)d_in[25];
  const float* a3b   = (const float*)d_in[26];
  const float* c1w   = (const float*)d_in[27];
  const float* c1b   = (const float*)d_in[28];
  const float* c2w   = (const float*)d_in[29];
  const float* c2b   = (const float*)d_in[30];
  const float* c3w   = (const float*)d_in[31];
  const float* c3b   = (const float*)d_in[32];
  const float* wmask = (const float*)d_in[33];

  float* ws = (float*)d_ws;
  const size_t R = (size_t)BB * DD;          // 524288 floats
  float* hx    = ws;                          // [B,512]
  float* gi    = ws + R;                      // [B,1536]
  float* table = ws + 4 * R;                  // [64,1536] (rows 0..49 used + junk)
  // encoder scratch aliases gi region (dead before rollout starts):
  float* P = gi;              // x0
  float* Q = gi + R;          // tA
  float* S = gi + 2 * R;      // tB
  float* U = ws + 4 * R + 2 * R;  // y/x scratch (beyond table, < 24 MiB total)
  float* out = (float*)d_out;

  dim3 blk(256);
  // gh table: rows v<64 of emb @ gwh + gbh (only v<50 ever gathered)
  sgemm_db<0, false, false><<<dim3(2, 24), blk, 0, stream>>>(emb, nullptr, 0, gwh, 1536, gbh, nullptr, table, 1536, 512);
  // encoder
  sgemm_db<0, false, true><<<dim3(32, 8), blk, 0, stream>>>(image, boxf, 2048, fr_w, 512, fr_b, nullptr, P, 512, 2304);
  lnorm_k<false, false><<<BB, blk, 0, stream>>>(P, nullptr, nullptr, nullptr, Q);
  sgemm_db<1, false, false><<<dim3(32, 8), blk, 0, stream>>>(Q, nullptr, 0, d1a_w, 512, d1a_b, nullptr, S, 512, 512);
  sgemm_db<0, false, false><<<dim3(32, 8), blk, 0, stream>>>(S, nullptr, 0, d1b_w, 512, d1b_b, nullptr, U, 512, 512);
  lnorm_k<false, true><<<BB, blk, 0, stream>>>(U, P, nullptr, nullptr, Q);
  sgemm_db<1, false, false><<<dim3(32, 8), blk, 0, stream>>>(Q, nullptr, 0, d2a_w, 512, d2a_b, nullptr, S, 512, 512);
  sgemm_db<0, true, false><<<dim3(32, 8), blk, 0, stream>>>(S, nullptr, 0, d2b_w, 512, d2b_b, P, U, 512, 512);
  lnorm_k<true, false><<<BB, blk, 0, stream>>>(U, nullptr, ln_g, ln_b, Q);
  sgemm_db<0, false, false><<<dim3(32, 8), blk, 0, stream>>>(Q, nullptr, 0, eo_w, 512, eo_b, nullptr, hx, 512, 512);

  // rollout: gi = hx @ gwi + gbi (r3-proven GEMM) ; fused GRU+heads per step
  for (int t = 0; t < TT; t++) {
    uint32_t fk0, fk1;
    tf2x32(0u, 1u, 0u, (uint32_t)t, fk0, fk1);   // fold_in(key(1), t)
    sgemm_db<0, false, false><<<dim3(32, 24), blk, 0, stream>>>(hx, nullptr, 0, gwi, 1536, gbi, nullptr, gi, 1536, 512);
    gru_head<<<BB, dim3(128), 0, stream>>>(gi, table, gbh, emb, hx,
                                           a1w, a1b, a2w, a2b, a3w, a3b,
                                           c1w, c1b, c2w, c2b, c3w, c3b,
                                           wmask, out, t, fk0, fk1);
  }
}